// Round 2
// baseline (504.111 us; speedup 1.0000x reference)
//
#include <hip/hip_runtime.h>
#include <hip/hip_bf16.h>
#include <stdint.h>

#define B_  2
#define S_  2048
#define H_  1024
#define NH_ 16
#define DH_ 64

typedef __attribute__((ext_vector_type(8))) short   s16x8;
typedef __attribute__((ext_vector_type(8))) __bf16  bf16x8;
typedef __attribute__((ext_vector_type(4))) float   f32x4;

__device__ __forceinline__ unsigned short f2bf(float f) {
  union { float f; uint32_t u; } v; v.f = f;
  uint32_t u = v.u;
  uint32_t r = (u + 0x7FFFu + ((u >> 16) & 1u)) >> 16;   // RNE
  return (unsigned short)r;
}

__device__ __forceinline__ void gll16(const void* g, void* l) {
  __builtin_amdgcn_global_load_lds(
      (__attribute__((address_space(1))) void*)(g),
      (__attribute__((address_space(3))) void*)(l), 16, 0, 0);
}

__device__ __forceinline__ f32x4 mfma_bf16(s16x8 a, s16x8 b, f32x4 c) {
  return __builtin_amdgcn_mfma_f32_16x16x32_bf16(
      __builtin_bit_cast(bf16x8, a), __builtin_bit_cast(bf16x8, b), c, 0, 0, 0);
}

// ---------------------------------------------------------------- convert
__global__ __launch_bounds__(256) void cvt_kernel(const float* __restrict__ src,
                                                  unsigned short* __restrict__ dst,
                                                  int n4) {
  int i = blockIdx.x * blockDim.x + threadIdx.x;
  int stride = gridDim.x * blockDim.x;
  for (; i < n4; i += stride) {
    float4 f = reinterpret_cast<const float4*>(src)[i];
    ushort4 o;
    o.x = f2bf(f.x); o.y = f2bf(f.y); o.z = f2bf(f.z); o.w = f2bf(f.w);
    reinterpret_cast<ushort4*>(dst)[i] = o;
  }
}

// ---------------------------------------------------------------- QKV GEMM
// C[m][n] = sum_k hs[m][k] * W[n][k] + bias[n]   (bt-GEMM, both row-major)
// z=0 -> Q  [B,NH,S,DH]; z=1 -> K same; z=2 -> V stored transposed [B,NH,DH,S]
__global__ __launch_bounds__(256) void qkv_gemm(
    const unsigned short* __restrict__ hsb,   // [4096][1024] bf16
    const unsigned short* __restrict__ Wb,    // [3][1024][1024] bf16
    const float* __restrict__ bq, const float* __restrict__ bk,
    const float* __restrict__ bv,
    unsigned short* __restrict__ Qb, unsigned short* __restrict__ Kb,
    unsigned short* __restrict__ Vtb)
{
  __shared__ alignas(16) unsigned short lA[128 * 64];
  __shared__ alignas(16) unsigned short lB[128 * 64];

  const int tid  = threadIdx.x;
  const int lane = tid & 63;
  const int wid  = tid >> 6;
  const int wrow = wid >> 1, wcol = wid & 1;
  const int z  = blockIdx.z;
  const int m0 = blockIdx.x * 128;
  const int n0 = blockIdx.y * 128;
  const int lr = lane & 15;
  const int lq = lane >> 4;

  const unsigned short* Wz = Wb + (size_t)z * (H_ * H_);

  f32x4 acc[4][4];
  #pragma unroll
  for (int i = 0; i < 4; ++i)
    #pragma unroll
    for (int j = 0; j < 4; ++j) acc[i][j] = {0.f, 0.f, 0.f, 0.f};

  for (int kt = 0; kt < H_ / 64; ++kt) {
    const int k0 = kt * 64;
    __syncthreads();
    // stage 128x64 bf16 tiles (8x16B chunks per 128B row), linear LDS dest,
    // inverse-swizzled global source (chunk c = cs ^ (row&7))
    #pragma unroll
    for (int i = 0; i < 4; ++i) {
      int idx = i * 256 + tid;
      int row = idx >> 3, cs = idx & 7, c = cs ^ (row & 7);
      gll16(hsb + (size_t)(m0 + row) * H_ + k0 + c * 8, (char*)lA + idx * 16);
    }
    #pragma unroll
    for (int i = 0; i < 4; ++i) {
      int idx = i * 256 + tid;
      int row = idx >> 3, cs = idx & 7, c = cs ^ (row & 7);
      gll16(Wz + (size_t)(n0 + row) * H_ + k0 + c * 8, (char*)lB + idx * 16);
    }
    __syncthreads();

    #pragma unroll
    for (int kk = 0; kk < 2; ++kk) {
      s16x8 af[4], bfr[4];
      #pragma unroll
      for (int mi = 0; mi < 4; ++mi) {
        int row = wrow * 64 + mi * 16 + lr;
        int ch  = (kk * 4 + lq) ^ (row & 7);
        af[mi] = *reinterpret_cast<const s16x8*>((const char*)lA + row * 128 + ch * 16);
      }
      #pragma unroll
      for (int ni = 0; ni < 4; ++ni) {
        int row = wcol * 64 + ni * 16 + lr;
        int ch  = (kk * 4 + lq) ^ (row & 7);
        bfr[ni] = *reinterpret_cast<const s16x8*>((const char*)lB + row * 128 + ch * 16);
      }
      #pragma unroll
      for (int mi = 0; mi < 4; ++mi)
        #pragma unroll
        for (int ni = 0; ni < 4; ++ni)
          acc[mi][ni] = mfma_bf16(af[mi], bfr[ni], acc[mi][ni]);
    }
  }

  const float* bvec = (z == 0) ? bq : (z == 1) ? bk : bv;

  // C/D layout: col n = lane&15, row m = (lane>>4)*4 + j
  #pragma unroll
  for (int ni = 0; ni < 4; ++ni) {
    int n = n0 + wcol * 64 + ni * 16 + lr;
    float bn = bvec[n];
    int h = n >> 6, d = n & 63;
    #pragma unroll
    for (int mi = 0; mi < 4; ++mi) {
      int mbase = m0 + wrow * 64 + mi * 16 + lq * 4;
      int b = mbase >> 11, s = mbase & 2047;
      if (z == 2) {
        ushort4 o;
        o.x = f2bf(acc[mi][ni][0] + bn);
        o.y = f2bf(acc[mi][ni][1] + bn);
        o.z = f2bf(acc[mi][ni][2] + bn);
        o.w = f2bf(acc[mi][ni][3] + bn);
        *reinterpret_cast<ushort4*>(Vtb + ((size_t)(b * NH_ + h) * DH_ + d) * S_ + s) = o;
      } else {
        unsigned short* dst = (z == 0) ? Qb : Kb;
        #pragma unroll
        for (int j = 0; j < 4; ++j)
          dst[((size_t)(b * NH_ + h) * S_ + (s + j)) * DH_ + d] =
              f2bf(acc[mi][ni][j] + bn);
      }
    }
  }
}

// ---------------------------------------------------------------- attention
// per block: 64 q-rows (4 waves x 16), KBLK=64 flash loop.
// swapped QK^T: D[kk][q] = mfma(K_frag, Q_frag)  -> softmax state per q=lane&15
// PV: D[d][q]  = mfma(Vt_frag, P_frag)           -> same column mapping, no shuffles
__global__ __launch_bounds__(256) void attn_kernel(
    const unsigned short* __restrict__ Qb,
    const unsigned short* __restrict__ Kb,
    const unsigned short* __restrict__ Vtb,
    const float* __restrict__ bias,
    float* __restrict__ out)
{
  __shared__ alignas(16) unsigned short lK[64 * 64];
  __shared__ alignas(16) unsigned short lV[64 * 64];
  __shared__ alignas(16) unsigned short lP[4][16 * 72];   // padded stride 72

  const int tid  = threadIdx.x;
  const int lane = tid & 63;
  const int wid  = tid >> 6;
  const int lr = lane & 15, lq = lane >> 4;

  const int q0 = blockIdx.x * 64;
  const int h  = blockIdx.y;
  const int b  = blockIdx.z;
  const int bh = b * NH_ + h;
  const int qrow = q0 + wid * 16 + lr;

  // Q fragments (B operand): Q[qrow][kt*32 + lq*8 + j]
  s16x8 qf[2];
  #pragma unroll
  for (int kt = 0; kt < 2; ++kt)
    qf[kt] = *reinterpret_cast<const s16x8*>(
        Qb + ((size_t)bh * S_ + qrow) * DH_ + kt * 32 + lq * 8);

  float m_run = -INFINITY, l_run = 0.0f;
  f32x4 acc_o[4];
  #pragma unroll
  for (int i = 0; i < 4; ++i) acc_o[i] = {0.f, 0.f, 0.f, 0.f};

  const float* brow = bias + ((size_t)h * S_ + qrow) * S_;
  unsigned short* Pw = &lP[wid][0];

  for (int kb = 0; kb < S_ / 64; ++kb) {
    __syncthreads();
    #pragma unroll
    for (int i = 0; i < 2; ++i) {
      int idx = i * 256 + tid;
      int row = idx >> 3, cs = idx & 7, c = cs ^ (row & 7);
      gll16(Kb + ((size_t)bh * S_ + kb * 64 + row) * DH_ + c * 8, (char*)lK + idx * 16);
    }
    #pragma unroll
    for (int i = 0; i < 2; ++i) {
      int idx = i * 256 + tid;
      int row = idx >> 3, cs = idx & 7, c = cs ^ (row & 7);
      gll16(Vtb + ((size_t)bh * DH_ + row) * S_ + kb * 64 + c * 8, (char*)lV + idx * 16);
    }

    // issue bias loads alongside staging — they drain at the same barrier,
    // hiding the 512MB stream's latency under the K/V staging + QK^T
    float4 b4[4];
    #pragma unroll
    for (int ct = 0; ct < 4; ++ct)
      b4[ct] = *reinterpret_cast<const float4*>(brow + kb * 64 + ct * 16 + lq * 4);

    __syncthreads();

    // QK^T
    f32x4 accs[4];
    #pragma unroll
    for (int ct = 0; ct < 4; ++ct) accs[ct] = {0.f, 0.f, 0.f, 0.f};
    #pragma unroll
    for (int ct = 0; ct < 4; ++ct) {
      #pragma unroll
      for (int kt = 0; kt < 2; ++kt) {
        int row = ct * 16 + lr;
        int ch  = (kt * 4 + lq) ^ (row & 7);
        s16x8 kf = *reinterpret_cast<const s16x8*>((const char*)lK + row * 128 + ch * 16);
        accs[ct] = mfma_bf16(kf, qf[kt], accs[ct]);
      }
    }

    // scores + bias, online softmax (lane holds 16 kk values of row q=lr)
    float p[16];
    #pragma unroll
    for (int ct = 0; ct < 4; ++ct) {
      p[ct * 4 + 0] = accs[ct][0] * 0.125f + b4[ct].x;
      p[ct * 4 + 1] = accs[ct][1] * 0.125f + b4[ct].y;
      p[ct * 4 + 2] = accs[ct][2] * 0.125f + b4[ct].z;
      p[ct * 4 + 3] = accs[ct][3] * 0.125f + b4[ct].w;
    }
    float tmax = -INFINITY;
    #pragma unroll
    for (int i = 0; i < 16; ++i) tmax = fmaxf(tmax, p[i]);
    tmax = fmaxf(tmax, __shfl_xor(tmax, 16));
    tmax = fmaxf(tmax, __shfl_xor(tmax, 32));

    float m_new = fmaxf(m_run, tmax);
    float alpha = __expf(m_run - m_new);   // first iter: exp(-inf)=0
    float lsum = 0.0f;
    #pragma unroll
    for (int i = 0; i < 16; ++i) { p[i] = __expf(p[i] - m_new); lsum += p[i]; }
    lsum += __shfl_xor(lsum, 16);
    lsum += __shfl_xor(lsum, 32);
    l_run = l_run * alpha + lsum;
    m_run = m_new;

    #pragma unroll
    for (int i = 0; i < 4; ++i) {
      acc_o[i][0] *= alpha; acc_o[i][1] *= alpha;
      acc_o[i][2] *= alpha; acc_o[i][3] *= alpha;
    }

    // P -> LDS (row q=lr, cols ct*16 + lq*4 + r), per-wave buffer
    #pragma unroll
    for (int ct = 0; ct < 4; ++ct) {
      ushort4 o;
      o.x = f2bf(p[ct * 4 + 0]); o.y = f2bf(p[ct * 4 + 1]);
      o.z = f2bf(p[ct * 4 + 2]); o.w = f2bf(p[ct * 4 + 3]);
      *reinterpret_cast<ushort4*>(Pw + lr * 72 + ct * 16 + lq * 4) = o;
    }

    // PV  (compiler orders the P write->read dependency through memory)
    #pragma unroll
    for (int kt = 0; kt < 2; ++kt) {
      s16x8 pf = *reinterpret_cast<const s16x8*>(Pw + lr * 72 + kt * 32 + lq * 8);
      #pragma unroll
      for (int df = 0; df < 4; ++df) {
        int row = df * 16 + lr;
        int ch  = (kt * 4 + lq) ^ (row & 7);
        s16x8 vf = *reinterpret_cast<const s16x8*>((const char*)lV + row * 128 + ch * 16);
        acc_o[df] = mfma_bf16(vf, pf, acc_o[df]);
      }
    }
  }

  // epilogue: acc_o[df][j] = ctx^T[d = df*16+lq*4+j][q = lr]
  float rl = 1.0f / l_run;
  float* orow = out + ((size_t)b * S_ + qrow) * H_ + h * DH_;
  #pragma unroll
  for (int df = 0; df < 4; ++df) {
    float4 o;
    o.x = acc_o[df][0] * rl; o.y = acc_o[df][1] * rl;
    o.z = acc_o[df][2] * rl; o.w = acc_o[df][3] * rl;
    *reinterpret_cast<float4*>(orow + df * 16 + lq * 4) = o;
  }
}

// ---------------------------------------------------------------- launch
extern "C" void kernel_launch(void* const* d_in, const int* in_sizes, int n_in,
                              void* d_out, int out_size, void* d_ws, size_t ws_size,
                              hipStream_t stream) {
  const float* hs   = (const float*)d_in[0];
  const float* bias = (const float*)d_in[1];
  const float* Wq   = (const float*)d_in[2];
  const float* bq   = (const float*)d_in[3];
  const float* Wk   = (const float*)d_in[4];
  const float* bk   = (const float*)d_in[5];
  const float* Wv   = (const float*)d_in[6];
  const float* bv   = (const float*)d_in[7];
  float* out = (float*)d_out;

  unsigned short* ws  = (unsigned short*)d_ws;
  unsigned short* hsb = ws;                                    // 8,388,608 elems
  unsigned short* Wb  = hsb + (size_t)B_ * S_ * H_;            // 3,145,728
  unsigned short* Qb  = Wb + (size_t)3 * H_ * H_;              // 8,388,608
  unsigned short* Kb  = Qb + (size_t)B_ * S_ * H_;             // 8,388,608
  unsigned short* Vtb = Kb + (size_t)B_ * S_ * H_;             // 8,388,608
  (void)in_sizes; (void)n_in; (void)out_size; (void)ws_size;

  cvt_kernel<<<2048, 256, 0, stream>>>(hs, hsb, (B_ * S_ * H_) / 4);
  cvt_kernel<<<1024, 256, 0, stream>>>(Wq, Wb, (H_ * H_) / 4);
  cvt_kernel<<<1024, 256, 0, stream>>>(Wk, Wb + H_ * H_, (H_ * H_) / 4);
  cvt_kernel<<<1024, 256, 0, stream>>>(Wv, Wb + 2 * H_ * H_, (H_ * H_) / 4);

  dim3 g1(32, 8, 3);
  qkv_gemm<<<g1, 256, 0, stream>>>(hsb, Wb, bq, bk, bv, Qb, Kb, Vtb);

  dim3 g2(32, NH_, B_);
  attn_kernel<<<g2, 256, 0, stream>>>(Qb, Kb, Vtb, bias, out);
}